// Round 11
// baseline (90.790 us; speedup 1.0000x reference)
//
#include <hip/hip_runtime.h>

// Problem constants (fixed by reference): B=8, H=32, S=64, C=4096, D=128
#define BB 8
#define HH 32
#define SS 64
#define CC 4096
#define DD 128
#define MAXU 2176   // per-batch compacted slot stride (used <= 2112)

// ---------------------------------------------------------------------------
// R11 = R9 (best measured: 47.9us) with the WHOLE PIPELINE LAUNCHED TWICE.
// Diagnostic round: all kernels are idempotent, so out is identical; the
// duration delta vs R9 measures total kernel+gap time T directly:
//   T = dur_new - 47.9 ;  fixed overhead F = 95.8 - dur_new.
// ---------------------------------------------------------------------------
// ws layout (units: 4-byte words) — every buffer write-before-read, no memset.
//   rowptr : 32832    adj : 16384    s : 32768    te : 16384
//   inv    : 17408    remap : 32768  nused : 64   Wt : 16384
//   ae_c   : 2228224  eg_c : 2228224
// ---------------------------------------------------------------------------

__global__ __launch_bounds__(1024) void build_graph(const int* __restrict__ hist,
                                                    const int* __restrict__ cur,
                                                    const float* __restrict__ W,
                                                    unsigned* __restrict__ rowptr,
                                                    unsigned* __restrict__ adj,
                                                    float* __restrict__ s,
                                                    unsigned* __restrict__ inv,
                                                    unsigned* __restrict__ remap,
                                                    unsigned* __restrict__ nused,
                                                    float* __restrict__ te,
                                                    float* __restrict__ Wt) {
    const int tid = threadIdx.x;
    if (blockIdx.x >= BB + 16) {                   // W transpose: 16 blocks
        int g = (blockIdx.x - BB - 16) * 1024 + tid;   // 16384 elems
        int k = g >> 7, n = g & 127;
        Wt[g] = W[n * 128 + k];
        return;
    }
    if (blockIdx.x >= BB) {                        // te table: 16 blocks
        int g = (blockIdx.x - BB) * 1024 + tid;    // S*256 = 16384
        int t = g >> 8, c = g & 255, k = c >> 1;
        float ang = (float)t * powf(10000.0f, -(float)k / 128.0f);
        te[g] = (c & 1) ? cosf(ang) : sinf(ang);
        return;
    }
    __shared__ unsigned table[4096];    // hash set of edge keys
    __shared__ unsigned cnt_a[4096];    // in-degree; later scatter cursors
    __shared__ unsigned cnt_b[4096];    // out-degree
    __shared__ unsigned used[4096];
    __shared__ unsigned pref[4096];
    __shared__ unsigned lkeys[2048];
    __shared__ unsigned wbase[17];
    __shared__ unsigned total;
    const int b = blockIdx.x;
    const int lane = tid & 63, wv = tid >> 6;

#pragma unroll
    for (int r = 0; r < 4; ++r) {
        int g = tid + r * 1024;
        table[g] = 0xFFFFFFFFu;
        cnt_a[g] = 0u;
        cnt_b[g] = 0u;
        used[g] = 0u;
    }
    if (tid == 0) total = 0u;
    __syncthreads();

    for (int t = tid; t < HH * SS; t += 1024) used[hist[b * HH * SS + t]] = 1u;
    if (tid < SS) used[cur[b * SS + tid]] = 1u;

    for (int t = tid; t < HH * (SS - 1); t += 1024) {   // edge dedupe
        int h = t / 63, ss = t - h * 63;
        int base = (b * HH + h) * SS + ss;
        int i = hist[base], j = hist[base + 1];
        if (i != j) {
            unsigned key = ((unsigned)i << 12) | (unsigned)j;
            unsigned hh = (key * 2654435761u) >> 20;
            for (;;) {
                hh &= 4095u;
                unsigned old = atomicCAS(&table[hh], 0xFFFFFFFFu, key);
                if (old == 0xFFFFFFFFu) {
                    unsigned slot = atomicAdd(&total, 1u);
                    lkeys[slot] = key;
                    atomicAdd(&cnt_a[key & 4095u], 1u);
                    atomicAdd(&cnt_b[key >> 12], 1u);
                    break;
                }
                if (old == key) break;
                ++hh;
            }
        }
    }
    __syncthreads();

#pragma unroll
    for (int r = 0; r < 4; ++r) {                  // s from in-degree
        int g = tid + r * 1024;
        s[b * CC + g] = sqrtf(1.0f + (float)cnt_a[g]);
    }

    // packed scan: v = (outdeg<<13)|used -> CSR rowptr + compact slot map
    {
        unsigned v0 = (cnt_b[tid * 4]     << 13) | used[tid * 4];
        unsigned v1 = (cnt_b[tid * 4 + 1] << 13) | used[tid * 4 + 1];
        unsigned v2 = (cnt_b[tid * 4 + 2] << 13) | used[tid * 4 + 2];
        unsigned v3 = (cnt_b[tid * 4 + 3] << 13) | used[tid * 4 + 3];
        unsigned tsum = v0 + v1 + v2 + v3;
        unsigned x = tsum;
#pragma unroll
        for (int off = 1; off < 64; off <<= 1) {
            unsigned y = __shfl_up(x, off);
            if (lane >= off) x += y;
        }
        if (lane == 63) wbase[wv + 1] = x;
        __syncthreads();
        if (tid == 0) {
            wbase[0] = 0u;
            for (int w = 1; w <= 16; ++w) wbase[w] += wbase[w - 1];
        }
        __syncthreads();
        unsigned texcl = wbase[wv] + x - tsum;
        pref[tid * 4]     = texcl;
        pref[tid * 4 + 1] = texcl + v0;
        pref[tid * 4 + 2] = texcl + v0 + v1;
        pref[tid * 4 + 3] = texcl + v0 + v1 + v2;
    }
#pragma unroll
    for (int r = 0; r < 4; ++r) cnt_a[tid + r * 1024] = 0u;   // scatter cursors
    __syncthreads();

#pragma unroll
    for (int r = 0; r < 4; ++r) {
        int g = tid + r * 1024;
        unsigned p = pref[g];
        rowptr[b * 4104 + g] = p >> 13;
        unsigned slot = p & 8191u;
        remap[b * CC + g] = slot;
        if (used[g]) inv[b * MAXU + slot] = (unsigned)g;
    }
    if (tid == 0) {
        rowptr[b * 4104 + 4096] = wbase[16] >> 13;
        nused[b] = wbase[16] & 8191u;
    }
    for (int e = tid; e < (int)total; e += 1024) { // adjacency scatter
        unsigned key = lkeys[e];
        unsigned i = key >> 12, j = key & 4095u;
        unsigned pos = (pref[i] >> 13) + atomicAdd(&cnt_a[i], 1u);
        adj[b * 2048 + pos] = j;
    }
}

// One WAVE per used row: ae = s_i*(s_i*E[i] + sum_{i->j} s_j*E[j]) -> ae_c.
__global__ __launch_bounds__(256) void ae_build(const float* __restrict__ E,
                                                const float* __restrict__ s,
                                                const unsigned* __restrict__ rowptr,
                                                const unsigned* __restrict__ adj,
                                                const unsigned* __restrict__ inv,
                                                const unsigned* __restrict__ nused,
                                                float* __restrict__ ae_c) {
    const int b = blockIdx.x / (MAXU / 4);                 // 544 blocks per batch
    const int slot = (blockIdx.x % (MAXU / 4)) * 4 + (threadIdx.x >> 6);
    const int lane = threadIdx.x & 63;
    if ((unsigned)slot >= nused[b]) return;
    unsigned c = inv[b * MAXU + slot];
    float si = s[b * CC + c];
    const float2* Eb = (const float2*)(E + (size_t)b * CC * DD);
    float2 e = Eb[(size_t)c * 64 + lane];
    float2 acc = make_float2(si * e.x, si * e.y);
    unsigned p0 = rowptr[b * 4104 + c], p1 = rowptr[b * 4104 + c + 1];
    for (unsigned p = p0; p < p1; ++p) {
        unsigned j = adj[b * 2048 + p];
        float sj = s[b * CC + j];
        float2 ej = Eb[(size_t)j * 64 + lane];
        acc.x += sj * ej.x;
        acc.y += sj * ej.y;
    }
    ((float2*)ae_c)[((size_t)b * MAXU + slot) * 64 + lane] =
        make_float2(si * acc.x, si * acc.y);
}

// Compact dense GEMM: eg_c = relu(ae_c @ W^T + bias). 32 rows/block,
// K-split LDS staging of Ws + As stride 131 (conflict-free reads).
__global__ __launch_bounds__(256) void gemm_eg(const float* __restrict__ ae_c,
                                               const float* __restrict__ Wt,
                                               const float* __restrict__ bg,
                                               const unsigned* __restrict__ nused,
                                               float* __restrict__ eg_c) {
    __shared__ float As[32][131];
    __shared__ float Ws[64][128];
    const int b = blockIdx.x / (MAXU / 32);                // 68 blocks per batch
    const int s0 = (blockIdx.x % (MAXU / 32)) * 32;
    const unsigned nu = nused[b];
    if ((unsigned)s0 >= nu) return;
    const int tid = threadIdx.x;

    // stage 32 ae rows (poison rows beyond nu are harmless f32 garbage)
    for (int idx = tid; idx < 1024; idx += 256) {
        int row = idx >> 5, f4 = idx & 31;
        float4 v = ((const float4*)ae_c)[((size_t)b * MAXU + s0 + row) * 32 + f4];
        As[row][f4 * 4]     = v.x;
        As[row][f4 * 4 + 1] = v.y;
        As[row][f4 * 4 + 2] = v.z;
        As[row][f4 * 4 + 3] = v.w;
    }

    const int tr = tid >> 4, tc = tid & 15;
    float bgv[8];
#pragma unroll
    for (int c = 0; c < 8; ++c) bgv[c] = bg[tc * 8 + c];
    float acc[2][8];
#pragma unroll
    for (int r = 0; r < 2; ++r)
#pragma unroll
        for (int c = 0; c < 8; ++c) acc[r][c] = 0.f;

    for (int kk = 0; kk < 128; kk += 64) {
        __syncthreads();                           // As ready / Ws reusable
        for (int idx = tid; idx < 64 * 128; idx += 256) {   // stage W half
            int kl = idx >> 7, n = idx & 127;
            Ws[kl][n] = Wt[(kk + kl) * 128 + n];   // coalesced
        }
        __syncthreads();
#pragma unroll 4
        for (int kl = 0; kl < 64; ++kl) {
            float a0 = As[tr * 2][kk + kl];        // 16 distinct banks
            float a1 = As[tr * 2 + 1][kk + kl];
            const float4* wp = (const float4*)&Ws[kl][tc * 8];
            float4 w0 = wp[0], w1 = wp[1];
            float wvv[8] = {w0.x, w0.y, w0.z, w0.w, w1.x, w1.y, w1.z, w1.w};
#pragma unroll
            for (int c = 0; c < 8; ++c) {
                acc[0][c] = fmaf(a0, wvv[c], acc[0][c]);
                acc[1][c] = fmaf(a1, wvv[c], acc[1][c]);
            }
        }
    }

#pragma unroll
    for (int r = 0; r < 2; ++r) {
        int row = tr * 2 + r;
        float4 o0, o1;
        o0.x = fmaxf(acc[r][0] + bgv[0], 0.f);
        o0.y = fmaxf(acc[r][1] + bgv[1], 0.f);
        o0.z = fmaxf(acc[r][2] + bgv[2], 0.f);
        o0.w = fmaxf(acc[r][3] + bgv[3], 0.f);
        o1.x = fmaxf(acc[r][4] + bgv[4], 0.f);
        o1.y = fmaxf(acc[r][5] + bgv[5], 0.f);
        o1.z = fmaxf(acc[r][6] + bgv[6], 0.f);
        o1.w = fmaxf(acc[r][7] + bgv[7], 0.f);
        float* outp = eg_c + ((size_t)b * MAXU + s0 + row) * 128 + tc * 8;
        ((float4*)outp)[0] = o0;
        ((float4*)outp)[1] = o1;
    }
}

// One wave per output row: out[row] = [eg_c[remap[cand]] | E[cand]] + te[s].
__global__ __launch_bounds__(256) void scatter_out(const int* __restrict__ hist,
                                                   const int* __restrict__ cur,
                                                   const unsigned* __restrict__ remap,
                                                   const float4* __restrict__ Egc4,
                                                   const float4* __restrict__ E4,
                                                   const float4* __restrict__ te4,
                                                   float4* __restrict__ out4) {
    int g = blockIdx.x * 256 + threadIdx.x;
    int row = g >> 6, lane = g & 63;
    int b, spos, cand;
    if (row < BB * HH * SS) {
        spos = row & 63;
        b = row >> 11;
        cand = hist[row];
    } else {
        int rc = row - BB * HH * SS;
        spos = rc & 63;
        b = rc >> 6;
        cand = cur[rc];
    }
    float4 v;
    if (lane < 32) {
        unsigned slot = remap[b * CC + cand];
        v = Egc4[((size_t)b * MAXU + slot) * 32 + lane];
    } else {
        v = E4[(size_t)(b * CC + cand) * 32 + (lane - 32)];
    }
    float4 t = te4[spos * 64 + lane];
    out4[(size_t)row * 64 + lane] = make_float4(v.x + t.x, v.y + t.y, v.z + t.z, v.w + t.w);
}

extern "C" void kernel_launch(void* const* d_in, const int* in_sizes, int n_in,
                              void* d_out, int out_size, void* d_ws, size_t ws_size,
                              hipStream_t stream) {
    const int*   hist = (const int*)d_in[1];
    const int*   cur  = (const int*)d_in[2];
    const float* E    = (const float*)d_in[3];
    const float* W    = (const float*)d_in[4];
    const float* bg   = (const float*)d_in[5];
    float* out = (float*)d_out;

    unsigned* ws_u   = (unsigned*)d_ws;
    unsigned* rowptr = ws_u;                         // 32832
    unsigned* adj    = rowptr + 32832;               // 16384
    float*    sarr   = (float*)(adj + 16384);        // 32768
    float*    te     = sarr + 32768;                 // 16384
    unsigned* inv    = (unsigned*)(te + 16384);      // 17408
    unsigned* remap  = inv + 17408;                  // 32768
    unsigned* nused  = remap + 32768;                // 64
    float*    Wt     = (float*)(nused + 64);         // 16384
    float*    ae_c   = Wt + 16384;                   // 2228224
    float*    eg_c   = ae_c + 2228224;               // 2228224

    // DIAGNOSTIC: full pipeline twice (idempotent). T = dur - 47.9, F = 95.8 - dur.
    for (int rep = 0; rep < 2; ++rep) {
        build_graph<<<BB + 32, 1024, 0, stream>>>(hist, cur, W, rowptr, adj, sarr,
                                                  inv, remap, nused, te, Wt);
        ae_build<<<BB * (MAXU / 4), 256, 0, stream>>>(E, sarr, rowptr, adj, inv,
                                                      nused, ae_c);
        gemm_eg<<<BB * (MAXU / 32), 256, 0, stream>>>(ae_c, Wt, bg, nused, eg_c);
        scatter_out<<<(BB * HH * SS + BB * SS) / 4, 256, 0, stream>>>(
            hist, cur, remap, (const float4*)eg_c, (const float4*)E,
            (const float4*)te, (float4*)out);
    }
}

// Round 12
// 40.404 us; speedup vs baseline: 2.2471x; 2.2471x over previous
//
#include <hip/hip_runtime.h>

// Problem constants (fixed by reference): B=8, H=32, S=64, C=4096, D=128
#define BB 8
#define HH 32
#define SS 64
#define CC 4096
#define DD 128
#define MAXU 2176   // per-batch compacted slot stride (used <= 2112)

typedef __attribute__((ext_vector_type(8))) short bf16x8;
typedef __attribute__((ext_vector_type(4))) float f32x4;

__device__ inline unsigned short f32_to_bf16_rtn(float f) {
    unsigned u = __float_as_uint(f);
    u += 0x7FFFu + ((u >> 16) & 1u);
    return (unsigned short)(u >> 16);
}

// ---------------------------------------------------------------------------
// ws layout (units: 4-byte words) — every buffer write-before-read, no memset.
//   rowptr : 32832    adj : 16384    s : 32768    te : 16384
//   inv    : 17408    remap : 32768  nused : 64
//   ae_c   : 2228224  eg_c : 2228224
// ---------------------------------------------------------------------------

// Blocks 0..7: per-batch graph build. Blocks 8..23: te table.
__global__ __launch_bounds__(1024) void build_graph(const int* __restrict__ hist,
                                                    const int* __restrict__ cur,
                                                    unsigned* __restrict__ rowptr,
                                                    unsigned* __restrict__ adj,
                                                    float* __restrict__ s,
                                                    unsigned* __restrict__ inv,
                                                    unsigned* __restrict__ remap,
                                                    unsigned* __restrict__ nused,
                                                    float* __restrict__ te) {
    const int tid = threadIdx.x;
    if (blockIdx.x >= BB) {                        // te table: 16 blocks
        int g = (blockIdx.x - BB) * 1024 + tid;    // S*256 = 16384
        int t = g >> 8, c = g & 255, k = c >> 1;
        float ang = (float)t * powf(10000.0f, -(float)k / 128.0f);
        te[g] = (c & 1) ? cosf(ang) : sinf(ang);
        return;
    }
    __shared__ unsigned table[4096];    // hash set of edge keys
    __shared__ unsigned cnt_a[4096];    // in-degree; later scatter cursors
    __shared__ unsigned cnt_b[4096];    // out-degree
    __shared__ unsigned used[4096];
    __shared__ unsigned pref[4096];
    __shared__ unsigned lkeys[2048];
    __shared__ unsigned wbase[17];
    __shared__ unsigned total;
    const int b = blockIdx.x;
    const int lane = tid & 63, wv = tid >> 6;

#pragma unroll
    for (int r = 0; r < 4; ++r) {
        int g = tid + r * 1024;
        table[g] = 0xFFFFFFFFu;
        cnt_a[g] = 0u;
        cnt_b[g] = 0u;
        used[g] = 0u;
    }
    if (tid == 0) total = 0u;
    __syncthreads();

    for (int t = tid; t < HH * SS; t += 1024) used[hist[b * HH * SS + t]] = 1u;
    if (tid < SS) used[cur[b * SS + tid]] = 1u;

    for (int t = tid; t < HH * (SS - 1); t += 1024) {   // edge dedupe
        int h = t / 63, ss = t - h * 63;
        int base = (b * HH + h) * SS + ss;
        int i = hist[base], j = hist[base + 1];
        if (i != j) {
            unsigned key = ((unsigned)i << 12) | (unsigned)j;
            unsigned hh = (key * 2654435761u) >> 20;
            for (;;) {
                hh &= 4095u;
                unsigned old = atomicCAS(&table[hh], 0xFFFFFFFFu, key);
                if (old == 0xFFFFFFFFu) {
                    unsigned slot = atomicAdd(&total, 1u);
                    lkeys[slot] = key;
                    atomicAdd(&cnt_a[key & 4095u], 1u);
                    atomicAdd(&cnt_b[key >> 12], 1u);
                    break;
                }
                if (old == key) break;
                ++hh;
            }
        }
    }
    __syncthreads();

#pragma unroll
    for (int r = 0; r < 4; ++r) {                  // s from in-degree
        int g = tid + r * 1024;
        s[b * CC + g] = sqrtf(1.0f + (float)cnt_a[g]);
    }

    // packed scan: v = (outdeg<<13)|used -> CSR rowptr + compact slot map
    {
        unsigned v0 = (cnt_b[tid * 4]     << 13) | used[tid * 4];
        unsigned v1 = (cnt_b[tid * 4 + 1] << 13) | used[tid * 4 + 1];
        unsigned v2 = (cnt_b[tid * 4 + 2] << 13) | used[tid * 4 + 2];
        unsigned v3 = (cnt_b[tid * 4 + 3] << 13) | used[tid * 4 + 3];
        unsigned tsum = v0 + v1 + v2 + v3;
        unsigned x = tsum;
#pragma unroll
        for (int off = 1; off < 64; off <<= 1) {
            unsigned y = __shfl_up(x, off);
            if (lane >= off) x += y;
        }
        if (lane == 63) wbase[wv + 1] = x;
        __syncthreads();
        if (tid == 0) {
            wbase[0] = 0u;
            for (int w = 1; w <= 16; ++w) wbase[w] += wbase[w - 1];
        }
        __syncthreads();
        unsigned texcl = wbase[wv] + x - tsum;
        pref[tid * 4]     = texcl;
        pref[tid * 4 + 1] = texcl + v0;
        pref[tid * 4 + 2] = texcl + v0 + v1;
        pref[tid * 4 + 3] = texcl + v0 + v1 + v2;
    }
#pragma unroll
    for (int r = 0; r < 4; ++r) cnt_a[tid + r * 1024] = 0u;   // scatter cursors
    __syncthreads();

#pragma unroll
    for (int r = 0; r < 4; ++r) {
        int g = tid + r * 1024;
        unsigned p = pref[g];
        rowptr[b * 4104 + g] = p >> 13;
        unsigned slot = p & 8191u;
        remap[b * CC + g] = slot;
        if (used[g]) inv[b * MAXU + slot] = (unsigned)g;
    }
    if (tid == 0) {
        rowptr[b * 4104 + 4096] = wbase[16] >> 13;
        nused[b] = wbase[16] & 8191u;
    }
    for (int e = tid; e < (int)total; e += 1024) { // adjacency scatter
        unsigned key = lkeys[e];
        unsigned i = key >> 12, j = key & 4095u;
        unsigned pos = (pref[i] >> 13) + atomicAdd(&cnt_a[i], 1u);
        adj[b * 2048 + pos] = j;
    }
}

// One WAVE per used row: ae = s_i*(s_i*E[i] + sum_{i->j} s_j*E[j]) -> ae_c.
__global__ __launch_bounds__(256) void ae_build(const float* __restrict__ E,
                                                const float* __restrict__ s,
                                                const unsigned* __restrict__ rowptr,
                                                const unsigned* __restrict__ adj,
                                                const unsigned* __restrict__ inv,
                                                const unsigned* __restrict__ nused,
                                                float* __restrict__ ae_c) {
    const int b = blockIdx.x / (MAXU / 4);                 // 544 blocks per batch
    const int slot = (blockIdx.x % (MAXU / 4)) * 4 + (threadIdx.x >> 6);
    const int lane = threadIdx.x & 63;
    if ((unsigned)slot >= nused[b]) return;
    unsigned c = inv[b * MAXU + slot];
    float si = s[b * CC + c];
    const float2* Eb = (const float2*)(E + (size_t)b * CC * DD);
    float2 e = Eb[(size_t)c * 64 + lane];
    float2 acc = make_float2(si * e.x, si * e.y);
    unsigned p0 = rowptr[b * 4104 + c], p1 = rowptr[b * 4104 + c + 1];
    for (unsigned p = p0; p < p1; ++p) {
        unsigned j = adj[b * 2048 + p];
        float sj = s[b * CC + j];
        float2 ej = Eb[(size_t)j * 64 + lane];
        acc.x += sj * ej.x;
        acc.y += sj * ej.y;
    }
    ((float2*)ae_c)[((size_t)b * MAXU + slot) * 64 + lane] =
        make_float2(si * acc.x, si * acc.y);
}

// MFMA GEMM: eg_c = relu(ae_c @ W^T + bias), bf16 inputs / f32 accumulate.
// R9's scalar loop was LDS-BW-bound (~40B LDS per 16 FMA per thread, ~712MB
// total). MFMA reads 16B/lane per operand for one 16x16x32 tile: ~10x less
// LDS traffic and the matrix pipe does the math. 32 rows/block, 4 waves as
// 2 row-groups x 2 col-groups; per wave: 4 k-steps x 4 n-tiles = 16 mfma.
// A: lane l holds row (l&15), k = 8*(l>>4)+e of the 16x32 tile.
// B: lane l holds col (l&15), k = 8*(l>>4)+e  -> read W in native [n][k].
// C/D (verified m89): col = lane&15, row = (lane>>4)*4 + reg.
__global__ __launch_bounds__(256) void gemm_eg(const float* __restrict__ ae_c,
                                               const float* __restrict__ W,
                                               const float* __restrict__ bg,
                                               const unsigned* __restrict__ nused,
                                               float* __restrict__ eg_c) {
    __shared__ unsigned short Abf[32][136];   // pad 136: row stride 272B -> 2-way (free)
    __shared__ unsigned short Wb[128][136];   // W in [n][k] layout, bf16
    const int b = blockIdx.x / (MAXU / 32);                // 68 blocks per batch
    const int s0 = (blockIdx.x % (MAXU / 32)) * 32;
    const unsigned nu = nused[b];
    if ((unsigned)s0 >= nu) return;
    const int tid = threadIdx.x;

    // stage ae tile: 32 rows x 128 f32 = 1024 float4 (rows contiguous in ae_c)
    for (int idx = tid; idx < 1024; idx += 256) {
        int row = idx >> 5, c4 = idx & 31;
        float4 v = ((const float4*)ae_c)[((size_t)b * MAXU + s0 + row) * 32 + c4];
        ushort4 o;
        o.x = f32_to_bf16_rtn(v.x); o.y = f32_to_bf16_rtn(v.y);
        o.z = f32_to_bf16_rtn(v.z); o.w = f32_to_bf16_rtn(v.w);
        *(ushort4*)&Abf[row][c4 * 4] = o;
    }
    // stage W: 128 rows x 128 f32 = 4096 float4, native [n][k] layout
    for (int idx = tid; idx < 4096; idx += 256) {
        int n = idx >> 5, c4 = idx & 31;
        float4 v = ((const float4*)W)[idx];
        ushort4 o;
        o.x = f32_to_bf16_rtn(v.x); o.y = f32_to_bf16_rtn(v.y);
        o.z = f32_to_bf16_rtn(v.z); o.w = f32_to_bf16_rtn(v.w);
        *(ushort4*)&Wb[n][c4 * 4] = o;
    }
    __syncthreads();

    const int lane = tid & 63, wv = tid >> 6;
    const int l15 = lane & 15, l4 = lane >> 4;
    const int r0 = (wv >> 1) * 16;            // wave row-group: rows r0..r0+15
    const int cb = (wv & 1) * 64;             // wave col-group: cols cb..cb+63

    f32x4 acc[4] = {{0.f, 0.f, 0.f, 0.f}, {0.f, 0.f, 0.f, 0.f},
                    {0.f, 0.f, 0.f, 0.f}, {0.f, 0.f, 0.f, 0.f}};
#pragma unroll
    for (int kt = 0; kt < 4; ++kt) {
        bf16x8 a = *(const bf16x8*)&Abf[r0 + l15][kt * 32 + l4 * 8];
#pragma unroll
        for (int nt = 0; nt < 4; ++nt) {
            bf16x8 bb = *(const bf16x8*)&Wb[cb + nt * 16 + l15][kt * 32 + l4 * 8];
            acc[nt] = __builtin_amdgcn_mfma_f32_16x16x32_bf16(a, bb, acc[nt], 0, 0, 0);
        }
    }

#pragma unroll
    for (int nt = 0; nt < 4; ++nt) {
        int col = cb + nt * 16 + l15;
        float bias = bg[col];
#pragma unroll
        for (int i = 0; i < 4; ++i) {
            int row = r0 + l4 * 4 + i;
            if ((unsigned)(s0 + row) < nu)
                eg_c[((size_t)b * MAXU + s0 + row) * 128 + col] =
                    fmaxf(acc[nt][i] + bias, 0.f);
        }
    }
}

// One wave per output row: out[row] = [eg_c[remap[cand]] | E[cand]] + te[s].
__global__ __launch_bounds__(256) void scatter_out(const int* __restrict__ hist,
                                                   const int* __restrict__ cur,
                                                   const unsigned* __restrict__ remap,
                                                   const float4* __restrict__ Egc4,
                                                   const float4* __restrict__ E4,
                                                   const float4* __restrict__ te4,
                                                   float4* __restrict__ out4) {
    int g = blockIdx.x * 256 + threadIdx.x;
    int row = g >> 6, lane = g & 63;
    int b, spos, cand;
    if (row < BB * HH * SS) {
        spos = row & 63;
        b = row >> 11;
        cand = hist[row];
    } else {
        int rc = row - BB * HH * SS;
        spos = rc & 63;
        b = rc >> 6;
        cand = cur[rc];
    }
    float4 v;
    if (lane < 32) {
        unsigned slot = remap[b * CC + cand];
        v = Egc4[((size_t)b * MAXU + slot) * 32 + lane];
    } else {
        v = E4[(size_t)(b * CC + cand) * 32 + (lane - 32)];
    }
    float4 t = te4[spos * 64 + lane];
    out4[(size_t)row * 64 + lane] = make_float4(v.x + t.x, v.y + t.y, v.z + t.z, v.w + t.w);
}

extern "C" void kernel_launch(void* const* d_in, const int* in_sizes, int n_in,
                              void* d_out, int out_size, void* d_ws, size_t ws_size,
                              hipStream_t stream) {
    const int*   hist = (const int*)d_in[1];
    const int*   cur  = (const int*)d_in[2];
    const float* E    = (const float*)d_in[3];
    const float* W    = (const float*)d_in[4];
    const float* bg   = (const float*)d_in[5];
    float* out = (float*)d_out;

    unsigned* ws_u   = (unsigned*)d_ws;
    unsigned* rowptr = ws_u;                         // 32832
    unsigned* adj    = rowptr + 32832;               // 16384
    float*    sarr   = (float*)(adj + 16384);        // 32768
    float*    te     = sarr + 32768;                 // 16384
    unsigned* inv    = (unsigned*)(te + 16384);      // 17408
    unsigned* remap  = inv + 17408;                  // 32768
    unsigned* nused  = remap + 32768;                // 64
    float*    ae_c   = (float*)(nused + 64);         // 2228224
    float*    eg_c   = ae_c + 2228224;               // 2228224

    build_graph<<<BB + 16, 1024, 0, stream>>>(hist, cur, rowptr, adj, sarr,
                                              inv, remap, nused, te);
    ae_build<<<BB * (MAXU / 4), 256, 0, stream>>>(E, sarr, rowptr, adj, inv,
                                                  nused, ae_c);
    gemm_eg<<<BB * (MAXU / 32), 256, 0, stream>>>(ae_c, W, bg, nused, eg_c);
    scatter_out<<<(BB * HH * SS + BB * SS) / 4, 256, 0, stream>>>(
        hist, cur, remap, (const float4*)eg_c, (const float4*)E,
        (const float4*)te, (float4*)out);
}

// Round 13
// 30.491 us; speedup vs baseline: 2.9776x; 1.3251x over previous
//
#include <hip/hip_runtime.h>

// Problem constants (fixed by reference): B=8, H=32, S=64, C=4096, D=128
#define BB 8
#define HH 32
#define SS 64
#define CC 4096
#define DD 128
#define MAXU 2176   // per-batch slot/occ stride (used <= 2112, occ == 2112)

typedef __attribute__((ext_vector_type(8))) short bf16x8;
typedef __attribute__((ext_vector_type(4))) float f32x4;

__device__ inline unsigned short f32_to_bf16_rtn(float f) {
    unsigned u = __float_as_uint(f);
    u += 0x7FFFu + ((u >> 16) & 1u);
    return (unsigned short)(u >> 16);
}
__device__ inline float bf16lo(unsigned u) { return __uint_as_float(u << 16); }
__device__ inline float bf16hi(unsigned u) { return __uint_as_float(u & 0xFFFF0000u); }

// ---------------------------------------------------------------------------
// Key algebra: relu((A'@E)@W^T + b) == relu(A'@(E@W^T) + b).  EW = E@W^T is a
// dense GEMM independent of the graph -> computed concurrently with the build
// inside one heterogeneous kernel; the sparse A'-apply + bias/relu + output
// scatter fuse into one wave-per-row tail kernel. 2 kernels total.
//
// ws layout (words), all write-before-read (0xAA-poison safe):
//   rowptr 32832 | adj 16384 | s 32768 | te 16384 | inv 17408 | nused 64
//   occp 32832 | occ_list 17408 | EWb (bf16) 2097152
// ---------------------------------------------------------------------------

// K1: blocks 0..7 per-batch graph build (dedupe->CSR, s, used-compaction,
// occurrence CSR); blocks 8..23 te table; blocks 24..535 MFMA EW tiles.
// Dynamic LDS union: build 73800B, gemm 52224B.
__global__ __launch_bounds__(1024) void mega(const int* __restrict__ hist,
                                             const int* __restrict__ cur,
                                             const float* __restrict__ E,
                                             const float* __restrict__ W,
                                             unsigned* __restrict__ rowptr,
                                             unsigned* __restrict__ adj,
                                             float* __restrict__ s,
                                             unsigned* __restrict__ inv,
                                             unsigned* __restrict__ nused,
                                             unsigned* __restrict__ occp,
                                             unsigned* __restrict__ occ_list,
                                             float* __restrict__ te,
                                             unsigned short* __restrict__ EWb) {
    extern __shared__ unsigned smem_u[];
    const int tid = threadIdx.x;

    if (blockIdx.x >= BB + 16) {                   // ---- EW GEMM tiles ----
        unsigned short* Abf = (unsigned short*)smem_u;         // [64][136]
        unsigned short* Wb  = Abf + 64 * 136;                  // [128][136]
        const int r0 = (blockIdx.x - BB - 16) * 64;            // global row
        // stage A tile (64 rows x 128 f32, rows contiguous)
        for (int idx = tid; idx < 2048; idx += 1024) {
            int row = idx >> 5, c4 = idx & 31;
            float4 v = ((const float4*)E)[(size_t)(r0 + row) * 32 + c4];
            ushort4 o;
            o.x = f32_to_bf16_rtn(v.x); o.y = f32_to_bf16_rtn(v.y);
            o.z = f32_to_bf16_rtn(v.z); o.w = f32_to_bf16_rtn(v.w);
            *(ushort4*)&Abf[row * 136 + c4 * 4] = o;
        }
        // stage W native [n][k]
        for (int idx = tid; idx < 4096; idx += 1024) {
            int n = idx >> 5, c4 = idx & 31;
            float4 v = ((const float4*)W)[idx];
            ushort4 o;
            o.x = f32_to_bf16_rtn(v.x); o.y = f32_to_bf16_rtn(v.y);
            o.z = f32_to_bf16_rtn(v.z); o.w = f32_to_bf16_rtn(v.w);
            *(ushort4*)&Wb[n * 136 + c4 * 4] = o;
        }
        __syncthreads();
        const int lane = tid & 63, wv = tid >> 6;
        const int l15 = lane & 15, l4 = lane >> 4;
        const int rb = (wv >> 2) * 16;             // wave row base (0..48)
        const int cb = (wv & 3) * 32;              // wave col base (0..96)
        f32x4 acc[2] = {{0.f, 0.f, 0.f, 0.f}, {0.f, 0.f, 0.f, 0.f}};
#pragma unroll
        for (int kt = 0; kt < 4; ++kt) {
            bf16x8 a = *(const bf16x8*)&Abf[(rb + l15) * 136 + kt * 32 + l4 * 8];
#pragma unroll
            for (int nt = 0; nt < 2; ++nt) {
                bf16x8 bb = *(const bf16x8*)&Wb[(cb + nt * 16 + l15) * 136 + kt * 32 + l4 * 8];
                acc[nt] = __builtin_amdgcn_mfma_f32_16x16x32_bf16(a, bb, acc[nt], 0, 0, 0);
            }
        }
#pragma unroll
        for (int nt = 0; nt < 2; ++nt) {
            int col = cb + nt * 16 + l15;
#pragma unroll
            for (int i = 0; i < 4; ++i) {
                int row = r0 + rb + l4 * 4 + i;
                EWb[(size_t)row * 128 + col] = f32_to_bf16_rtn(acc[nt][i]);
            }
        }
        return;
    }
    if (blockIdx.x >= BB) {                        // ---- te table ----
        int g = (blockIdx.x - BB) * 1024 + tid;    // S*256 = 16384
        int t = g >> 8, c = g & 255, k = c >> 1;
        float ang = (float)t * powf(10000.0f, -(float)k / 128.0f);
        te[g] = (c & 1) ? cosf(ang) : sinf(ang);
        return;
    }

    // ---- graph build (one block per batch) ----
    unsigned* table  = smem_u;              // 4096 hash set of edge keys
    unsigned* cntAB  = table + 4096;        // in-deg low16 | out-deg high16; cursors
    unsigned* cntOcc = cntAB + 4096;        // occurrence counts
    unsigned* pref   = cntOcc + 4096;       // scan output
    unsigned* lkeys  = pref + 4096;         // 2048 unique edge keys
    unsigned* wbase  = lkeys + 2048;        // 17
    unsigned* totalp = wbase + 17;
    const int b = blockIdx.x;
    const int lane = tid & 63, wv = tid >> 6;

#pragma unroll
    for (int r = 0; r < 4; ++r) {
        int g = tid + r * 1024;
        table[g] = 0xFFFFFFFFu;
        cntAB[g] = 0u;
        cntOcc[g] = 0u;
    }
    if (tid == 0) *totalp = 0u;
    __syncthreads();

    // occurrence counting (hist + cur)
    for (int t = tid; t < HH * SS; t += 1024) atomicAdd(&cntOcc[hist[b * HH * SS + t]], 1u);
    if (tid < SS) atomicAdd(&cntOcc[cur[b * SS + tid]], 1u);

    // edge dedupe
    for (int t = tid; t < HH * (SS - 1); t += 1024) {
        int h = t / 63, ss = t - h * 63;
        int base = (b * HH + h) * SS + ss;
        int i = hist[base], j = hist[base + 1];
        if (i != j) {
            unsigned key = ((unsigned)i << 12) | (unsigned)j;
            unsigned hh = (key * 2654435761u) >> 20;
            for (;;) {
                hh &= 4095u;
                unsigned old = atomicCAS(&table[hh], 0xFFFFFFFFu, key);
                if (old == 0xFFFFFFFFu) {
                    unsigned slot = atomicAdd(totalp, 1u);
                    lkeys[slot] = key;
                    atomicAdd(&cntAB[key & 4095u], 1u);         // in-degree
                    atomicAdd(&cntAB[key >> 12], 1u << 16);     // out-degree
                    break;
                }
                if (old == key) break;
                ++hh;
            }
        }
    }
    __syncthreads();

#pragma unroll
    for (int r = 0; r < 4; ++r) {                  // s from in-degree
        int g = tid + r * 1024;
        s[b * CC + g] = sqrtf(1.0f + (float)(cntAB[g] & 0xFFFFu));
    }

    // scan #1: v = (outdeg<<13) | used  -> CSR rowptr + compact slot map
    {
        unsigned v0 = ((cntAB[tid * 4]     >> 16) << 13) | (cntOcc[tid * 4]     ? 1u : 0u);
        unsigned v1 = ((cntAB[tid * 4 + 1] >> 16) << 13) | (cntOcc[tid * 4 + 1] ? 1u : 0u);
        unsigned v2 = ((cntAB[tid * 4 + 2] >> 16) << 13) | (cntOcc[tid * 4 + 2] ? 1u : 0u);
        unsigned v3 = ((cntAB[tid * 4 + 3] >> 16) << 13) | (cntOcc[tid * 4 + 3] ? 1u : 0u);
        unsigned tsum = v0 + v1 + v2 + v3;
        unsigned x = tsum;
#pragma unroll
        for (int off = 1; off < 64; off <<= 1) {
            unsigned y = __shfl_up(x, off);
            if (lane >= off) x += y;
        }
        if (lane == 63) wbase[wv + 1] = x;
        __syncthreads();
        if (tid == 0) {
            wbase[0] = 0u;
            for (int w = 1; w <= 16; ++w) wbase[w] += wbase[w - 1];
        }
        __syncthreads();
        unsigned texcl = wbase[wv] + x - tsum;
        pref[tid * 4]     = texcl;
        pref[tid * 4 + 1] = texcl + v0;
        pref[tid * 4 + 2] = texcl + v0 + v1;
        pref[tid * 4 + 3] = texcl + v0 + v1 + v2;
        __syncthreads();
#pragma unroll
        for (int r = 0; r < 4; ++r) {
            int g = tid + r * 1024;
            unsigned p = pref[g];
            rowptr[b * 4104 + g] = p >> 13;
            if (cntOcc[g]) inv[b * MAXU + (p & 8191u)] = (unsigned)g;
        }
        if (tid == 0) {
            rowptr[b * 4104 + 4096] = wbase[16] >> 13;
            nused[b] = wbase[16] & 8191u;
        }
    }
    __syncthreads();
#pragma unroll
    for (int r = 0; r < 4; ++r) cntAB[tid + r * 1024] = 0u;   // edge cursors
    __syncthreads();

    {   // adjacency scatter in CSR order
        unsigned total = *totalp;
        for (int e = tid; e < (int)total; e += 1024) {
            unsigned key = lkeys[e];
            unsigned i = key >> 12, j = key & 4095u;
            unsigned pos = (pref[i] >> 13) + atomicAdd(&cntAB[i], 1u);
            adj[b * 2048 + pos] = j;
        }
    }
    __syncthreads();                                // pref reads done

    // scan #2 over occurrence counts -> occp
    {
        unsigned v0 = cntOcc[tid * 4], v1 = cntOcc[tid * 4 + 1];
        unsigned v2 = cntOcc[tid * 4 + 2], v3 = cntOcc[tid * 4 + 3];
        unsigned tsum = v0 + v1 + v2 + v3;
        unsigned x = tsum;
#pragma unroll
        for (int off = 1; off < 64; off <<= 1) {
            unsigned y = __shfl_up(x, off);
            if (lane >= off) x += y;
        }
        if (lane == 63) wbase[wv + 1] = x;
        __syncthreads();
        if (tid == 0) {
            wbase[0] = 0u;
            for (int w = 1; w <= 16; ++w) wbase[w] += wbase[w - 1];
        }
        __syncthreads();
        unsigned texcl = wbase[wv] + x - tsum;
        pref[tid * 4]     = texcl;
        pref[tid * 4 + 1] = texcl + v0;
        pref[tid * 4 + 2] = texcl + v0 + v1;
        pref[tid * 4 + 3] = texcl + v0 + v1 + v2;
        __syncthreads();
#pragma unroll
        for (int r = 0; r < 4; ++r) {
            int g = tid + r * 1024;
            occp[b * 4104 + g] = pref[g];
        }
        if (tid == 0) occp[b * 4104 + 4096] = wbase[16];
    }
    __syncthreads();
#pragma unroll
    for (int r = 0; r < 4; ++r) cntAB[tid + r * 1024] = 0u;   // occ cursors
    __syncthreads();

    for (int t = tid; t < HH * SS; t += 1024) {    // hist occurrences
        int cand = hist[b * HH * SS + t];
        unsigned pos = pref[cand] + atomicAdd(&cntAB[cand], 1u);
        occ_list[b * MAXU + pos] = ((unsigned)(b * 2048 + t) << 6) | (unsigned)(t & 63);
    }
    if (tid < SS) {                                // cur occurrences
        int cand = cur[b * SS + tid];
        unsigned pos = pref[cand] + atomicAdd(&cntAB[cand], 1u);
        occ_list[b * MAXU + pos] =
            ((unsigned)(BB * HH * SS + b * SS + tid) << 6) | (unsigned)tid;
    }
}

// K2: wave per used row. eg = relu(s_i*(s_i*EW[c] + sum_{c->j} s_j*EW[j]) + bg)
// in registers (cols 2l,2l+1 per lane), then write every occurrence
// out[row] = [eg | E[c]] + te[spos] directly. No eg_c/ae_c intermediates.
__global__ __launch_bounds__(256) void apply_scatter(const float* __restrict__ E,
                                                     const float* __restrict__ s,
                                                     const unsigned* __restrict__ rowptr,
                                                     const unsigned* __restrict__ adj,
                                                     const unsigned* __restrict__ inv,
                                                     const unsigned* __restrict__ nused,
                                                     const unsigned short* __restrict__ EWb,
                                                     const float* __restrict__ bg,
                                                     const unsigned* __restrict__ occp,
                                                     const unsigned* __restrict__ occ_list,
                                                     const float* __restrict__ te,
                                                     float* __restrict__ out) {
    const int b = blockIdx.x / (MAXU / 4);
    const int slot = (blockIdx.x % (MAXU / 4)) * 4 + (threadIdx.x >> 6);
    const int lane = threadIdx.x & 63;
    if ((unsigned)slot >= nused[b]) return;
    const unsigned c = inv[b * MAXU + slot];
    const float si = s[b * CC + c];
    const unsigned* ew = (const unsigned*)EWb;     // 64 u32 per row (128 bf16)

    unsigned u = ew[(size_t)(b * CC + c) * 64 + lane];
    float ax = si * bf16lo(u), ay = si * bf16hi(u);
    unsigned p0 = rowptr[b * 4104 + c], p1 = rowptr[b * 4104 + c + 1];
    for (unsigned p = p0; p < p1; ++p) {
        unsigned j = adj[b * 2048 + p];
        float sj = s[b * CC + j];
        unsigned uj = ew[(size_t)(b * CC + j) * 64 + lane];
        ax += sj * bf16lo(uj);
        ay += sj * bf16hi(uj);
    }
    float2 bgv = ((const float2*)bg)[lane];
    ax = fmaxf(si * ax + bgv.x, 0.f);
    ay = fmaxf(si * ay + bgv.y, 0.f);
    float2 e = ((const float2*)E)[(size_t)(b * CC + c) * 64 + lane];

    const float2* te2 = (const float2*)te;
    float2* out2 = (float2*)out;
    unsigned o0 = occp[b * 4104 + c], o1 = occp[b * 4104 + c + 1];
    for (unsigned o = o0; o < o1; ++o) {
        unsigned ent = occ_list[b * MAXU + o];
        unsigned outrow = ent >> 6, spos = ent & 63u;
        float2 t0 = te2[spos * 128 + lane];
        float2 t1 = te2[spos * 128 + 64 + lane];
        out2[(size_t)outrow * 128 + lane]      = make_float2(ax + t0.x, ay + t0.y);
        out2[(size_t)outrow * 128 + 64 + lane] = make_float2(e.x + t1.x, e.y + t1.y);
    }
}

extern "C" void kernel_launch(void* const* d_in, const int* in_sizes, int n_in,
                              void* d_out, int out_size, void* d_ws, size_t ws_size,
                              hipStream_t stream) {
    const int*   hist = (const int*)d_in[1];
    const int*   cur  = (const int*)d_in[2];
    const float* E    = (const float*)d_in[3];
    const float* W    = (const float*)d_in[4];
    const float* bg   = (const float*)d_in[5];
    float* out = (float*)d_out;

    unsigned* ws_u     = (unsigned*)d_ws;
    unsigned* rowptr   = ws_u;                        // 32832
    unsigned* adj      = rowptr + 32832;              // 16384
    float*    sarr     = (float*)(adj + 16384);       // 32768
    float*    te       = sarr + 32768;                // 16384
    unsigned* inv      = (unsigned*)(te + 16384);     // 17408
    unsigned* nused    = inv + 17408;                 // 64
    unsigned* occp     = nused + 64;                  // 32832
    unsigned* occ_list = occp + 32832;                // 17408
    unsigned short* EWb = (unsigned short*)(occ_list + 17408);  // 4194304 shorts

    mega<<<BB + 16 + 512, 1024, 73856, stream>>>(hist, cur, E, W, rowptr, adj,
                                                 sarr, inv, nused, occp,
                                                 occ_list, te, EWb);
    apply_scatter<<<BB * (MAXU / 4), 256, 0, stream>>>(E, sarr, rowptr, adj, inv,
                                                       nused, EWb, bg, occp,
                                                       occ_list, te, out);
}

// Round 14
// 25.604 us; speedup vs baseline: 3.5459x; 1.1909x over previous
//
#include <hip/hip_runtime.h>

// Problem constants (fixed by reference): B=8, H=32, S=64, C=4096, D=128
#define BB 8
#define HH 32
#define SS 64
#define CC 4096
#define DD 128

typedef __attribute__((ext_vector_type(8))) short bf16x8;
typedef __attribute__((ext_vector_type(4))) float f32x4;

__device__ inline unsigned short f32_to_bf16_rtn(float f) {
    unsigned u = __float_as_uint(f);
    u += 0x7FFFu + ((u >> 16) & 1u);
    return (unsigned short)(u >> 16);
}
__device__ inline float bf16lo(unsigned u) { return __uint_as_float(u << 16); }
__device__ inline float bf16hi(unsigned u) { return __uint_as_float(u & 0xFFFF0000u); }

// ---------------------------------------------------------------------------
// Algebra: relu((A'@E)@W^T + b) == relu(A'@(E@W^T) + b).  EW = E@W^T is
// graph-independent -> computed in heterogeneous K1 concurrently with the
// per-batch graph build.  K2 is wave-per-OUTPUT-row: cand = hist/cur[row],
// eg = relu(s_c*(s_c*EW[c] + sum_{c->j} s_j*EW[j]) + bg), out = [eg|E[c]]+te.
// No used-compaction / occurrence CSR at all (R13 carried both; the build
// block was K1's critical path and occ machinery was ~40% of it).
//
// ws layout (words), all write-before-read (0xAA-poison safe):
//   rowptr 32832 | adj 16384 | s 32768 | te 16384 | EWb (bf16) 2097152
// ---------------------------------------------------------------------------

// K1: blocks 0..7 per-batch graph build (dedupe->CSR + s); blocks 8..23 te
// table; blocks 24..535 MFMA EW tiles. Dynamic LDS union: build 41KB,
// gemm 52.2KB -> smem 52224B = 3 blocks/CU.
__global__ __launch_bounds__(1024) void mega(const int* __restrict__ hist,
                                             const int* __restrict__ cur,
                                             const float* __restrict__ E,
                                             const float* __restrict__ W,
                                             unsigned* __restrict__ rowptr,
                                             unsigned* __restrict__ adj,
                                             float* __restrict__ s,
                                             float* __restrict__ te,
                                             unsigned short* __restrict__ EWb) {
    extern __shared__ unsigned smem_u[];
    const int tid = threadIdx.x;

    if (blockIdx.x >= BB + 16) {                   // ---- EW GEMM tiles ----
        unsigned short* Abf = (unsigned short*)smem_u;         // [64][136]
        unsigned short* Wb  = Abf + 64 * 136;                  // [128][136]
        const int r0 = (blockIdx.x - BB - 16) * 64;            // global row
        for (int idx = tid; idx < 2048; idx += 1024) {         // stage E tile
            int row = idx >> 5, c4 = idx & 31;
            float4 v = ((const float4*)E)[(size_t)(r0 + row) * 32 + c4];
            ushort4 o;
            o.x = f32_to_bf16_rtn(v.x); o.y = f32_to_bf16_rtn(v.y);
            o.z = f32_to_bf16_rtn(v.z); o.w = f32_to_bf16_rtn(v.w);
            *(ushort4*)&Abf[row * 136 + c4 * 4] = o;
        }
        for (int idx = tid; idx < 4096; idx += 1024) {         // stage W [n][k]
            int n = idx >> 5, c4 = idx & 31;
            float4 v = ((const float4*)W)[idx];
            ushort4 o;
            o.x = f32_to_bf16_rtn(v.x); o.y = f32_to_bf16_rtn(v.y);
            o.z = f32_to_bf16_rtn(v.z); o.w = f32_to_bf16_rtn(v.w);
            *(ushort4*)&Wb[n * 136 + c4 * 4] = o;
        }
        __syncthreads();
        const int lane = tid & 63, wv = tid >> 6;
        const int l15 = lane & 15, l4 = lane >> 4;
        const int rb = (wv >> 2) * 16;             // wave row base (0..48)
        const int cb = (wv & 3) * 32;              // wave col base (0..96)
        f32x4 acc[2] = {{0.f, 0.f, 0.f, 0.f}, {0.f, 0.f, 0.f, 0.f}};
#pragma unroll
        for (int kt = 0; kt < 4; ++kt) {
            bf16x8 a = *(const bf16x8*)&Abf[(rb + l15) * 136 + kt * 32 + l4 * 8];
#pragma unroll
            for (int nt = 0; nt < 2; ++nt) {
                bf16x8 bb = *(const bf16x8*)&Wb[(cb + nt * 16 + l15) * 136 + kt * 32 + l4 * 8];
                acc[nt] = __builtin_amdgcn_mfma_f32_16x16x32_bf16(a, bb, acc[nt], 0, 0, 0);
            }
        }
#pragma unroll
        for (int nt = 0; nt < 2; ++nt) {
            int col = cb + nt * 16 + l15;
#pragma unroll
            for (int i = 0; i < 4; ++i) {
                int row = r0 + rb + l4 * 4 + i;
                EWb[(size_t)row * 128 + col] = f32_to_bf16_rtn(acc[nt][i]);
            }
        }
        return;
    }
    if (blockIdx.x >= BB) {                        // ---- te table ----
        int g = (blockIdx.x - BB) * 1024 + tid;    // S*256 = 16384
        int t = g >> 8, c = g & 255, k = c >> 1;
        float ang = (float)t * powf(10000.0f, -(float)k / 128.0f);
        te[g] = (c & 1) ? cosf(ang) : sinf(ang);
        return;
    }

    // ---- graph build (one block per batch) ----
    unsigned* table = smem_u;              // 4096 hash set; ALIASED as pref later
    unsigned* cnt   = table + 4096;        // in-deg low16 | out-deg high16; cursors
    unsigned* lkeys = cnt + 4096;          // 2048 unique edge keys
    unsigned* wbase = lkeys + 2048;        // 17
    unsigned* totalp = wbase + 17;
    const int b = blockIdx.x;
    const int lane = tid & 63, wv = tid >> 6;

#pragma unroll
    for (int r = 0; r < 4; ++r) {
        int g = tid + r * 1024;
        table[g] = 0xFFFFFFFFu;
        cnt[g] = 0u;
    }
    if (tid == 0) *totalp = 0u;
    __syncthreads();

    for (int t = tid; t < HH * (SS - 1); t += 1024) {   // edge dedupe
        int h = t / 63, ss = t - h * 63;
        int base = (b * HH + h) * SS + ss;
        int i = hist[base], j = hist[base + 1];
        if (i != j) {
            unsigned key = ((unsigned)i << 12) | (unsigned)j;
            unsigned hh = (key * 2654435761u) >> 20;
            for (;;) {
                hh &= 4095u;
                unsigned old = atomicCAS(&table[hh], 0xFFFFFFFFu, key);
                if (old == 0xFFFFFFFFu) {
                    unsigned slot = atomicAdd(totalp, 1u);
                    lkeys[slot] = key;
                    atomicAdd(&cnt[key & 4095u], 1u);         // in-degree
                    atomicAdd(&cnt[key >> 12], 1u << 16);     // out-degree
                    break;
                }
                if (old == key) break;
                ++hh;
            }
        }
    }
    __syncthreads();                               // table (hash) now dead

#pragma unroll
    for (int r = 0; r < 4; ++r) {                  // s from in-degree
        int g = tid + r * 1024;
        s[b * CC + g] = sqrtf(1.0f + (float)(cnt[g] & 0xFFFFu));
    }

    // scan over out-degree -> CSR rowptr (pref aliases the dead hash table)
    unsigned* pref = table;
    {
        unsigned v0 = cnt[tid * 4]     >> 16;
        unsigned v1 = cnt[tid * 4 + 1] >> 16;
        unsigned v2 = cnt[tid * 4 + 2] >> 16;
        unsigned v3 = cnt[tid * 4 + 3] >> 16;
        unsigned tsum = v0 + v1 + v2 + v3;
        unsigned x = tsum;
#pragma unroll
        for (int off = 1; off < 64; off <<= 1) {
            unsigned y = __shfl_up(x, off);
            if (lane >= off) x += y;
        }
        if (lane == 63) wbase[wv + 1] = x;
        __syncthreads();
        if (tid == 0) {
            wbase[0] = 0u;
            for (int w = 1; w <= 16; ++w) wbase[w] += wbase[w - 1];
        }
        __syncthreads();
        unsigned texcl = wbase[wv] + x - tsum;
        pref[tid * 4]     = texcl;
        pref[tid * 4 + 1] = texcl + v0;
        pref[tid * 4 + 2] = texcl + v0 + v1;
        pref[tid * 4 + 3] = texcl + v0 + v1 + v2;
        __syncthreads();
#pragma unroll
        for (int r = 0; r < 4; ++r) {
            int g = tid + r * 1024;
            rowptr[b * 4104 + g] = pref[g];
        }
        if (tid == 0) rowptr[b * 4104 + 4096] = wbase[16];
    }
    __syncthreads();
#pragma unroll
    for (int r = 0; r < 4; ++r) cnt[tid + r * 1024] = 0u;   // scatter cursors
    __syncthreads();

    {   // adjacency scatter in CSR order
        unsigned total = *totalp;
        for (int e = tid; e < (int)total; e += 1024) {
            unsigned key = lkeys[e];
            unsigned i = key >> 12, j = key & 4095u;
            unsigned pos = pref[i] + atomicAdd(&cnt[i], 1u);
            adj[b * 2048 + pos] = j;
        }
    }
}

// K2: one wave per OUTPUT row. cand uniform per wave (scalar chain), EW/E/te
// vector reads per lane, one coalesced 1KB row write. No inv/occ indirection.
__global__ __launch_bounds__(256) void apply_out(const int* __restrict__ hist,
                                                 const int* __restrict__ cur,
                                                 const float* __restrict__ E,
                                                 const float* __restrict__ s,
                                                 const unsigned* __restrict__ rowptr,
                                                 const unsigned* __restrict__ adj,
                                                 const unsigned short* __restrict__ EWb,
                                                 const float* __restrict__ bg,
                                                 const float* __restrict__ te,
                                                 float* __restrict__ out) {
    const int g = blockIdx.x * 256 + threadIdx.x;
    const int row = g >> 6, lane = g & 63;
    int b, spos, cand;
    if (row < BB * HH * SS) {
        spos = row & 63;
        b = row >> 11;
        cand = hist[row];
    } else {
        int rc = row - BB * HH * SS;
        spos = rc & 63;
        b = rc >> 6;
        cand = cur[rc];
    }
    const unsigned* ew = (const unsigned*)EWb;     // 64 u32 per row (128 bf16)
    const float si = s[b * CC + cand];
    unsigned u = ew[(size_t)(b * CC + cand) * 64 + lane];
    float ax = si * bf16lo(u), ay = si * bf16hi(u);
    unsigned p0 = rowptr[b * 4104 + cand], p1 = rowptr[b * 4104 + cand + 1];
    for (unsigned p = p0; p < p1; ++p) {
        unsigned j = adj[b * 2048 + p];
        float sj = s[b * CC + j];
        unsigned uj = ew[(size_t)(b * CC + j) * 64 + lane];
        ax += sj * bf16lo(uj);
        ay += sj * bf16hi(uj);
    }
    float2 bgv = ((const float2*)bg)[lane];
    ax = fmaxf(si * ax + bgv.x, 0.f);
    ay = fmaxf(si * ay + bgv.y, 0.f);
    float2 e = ((const float2*)E)[(size_t)(b * CC + cand) * 64 + lane];

    const float2* te2 = (const float2*)te;
    float2 t0 = te2[spos * 128 + lane];
    float2 t1 = te2[spos * 128 + 64 + lane];
    float2* out2 = (float2*)out;
    out2[(size_t)row * 128 + lane]      = make_float2(ax + t0.x, ay + t0.y);
    out2[(size_t)row * 128 + 64 + lane] = make_float2(e.x + t1.x, e.y + t1.y);
}

extern "C" void kernel_launch(void* const* d_in, const int* in_sizes, int n_in,
                              void* d_out, int out_size, void* d_ws, size_t ws_size,
                              hipStream_t stream) {
    const int*   hist = (const int*)d_in[1];
    const int*   cur  = (const int*)d_in[2];
    const float* E    = (const float*)d_in[3];
    const float* W    = (const float*)d_in[4];
    const float* bg   = (const float*)d_in[5];
    float* out = (float*)d_out;

    unsigned* ws_u   = (unsigned*)d_ws;
    unsigned* rowptr = ws_u;                          // 32832
    unsigned* adj    = rowptr + 32832;                // 16384
    float*    sarr   = (float*)(adj + 16384);         // 32768
    float*    te     = sarr + 32768;                  // 16384
    unsigned short* EWb = (unsigned short*)(te + 16384);  // 4194304 shorts

    mega<<<BB + 16 + 512, 1024, 52224, stream>>>(hist, cur, E, W, rowptr, adj,
                                                 sarr, te, EWb);
    apply_out<<<(BB * HH * SS + BB * SS) / 4, 256, 0, stream>>>(
        hist, cur, E, sarr, rowptr, adj, EWb, bg, te, out);
}

// Round 15
// 25.488 us; speedup vs baseline: 3.5621x; 1.0046x over previous
//
#include <hip/hip_runtime.h>

// Problem constants (fixed by reference): B=8, H=32, S=64, C=4096, D=128
#define BB 8
#define HH 32
#define SS 64
#define CC 4096
#define DD 128

typedef __attribute__((ext_vector_type(8))) short bf16x8;
typedef __attribute__((ext_vector_type(4))) float f32x4;

__device__ inline unsigned short f32_to_bf16_rtn(float f) {
    unsigned u = __float_as_uint(f);
    u += 0x7FFFu + ((u >> 16) & 1u);
    return (unsigned short)(u >> 16);
}
__device__ inline float bf16lo(unsigned u) { return __uint_as_float(u << 16); }
__device__ inline float bf16hi(unsigned u) { return __uint_as_float(u & 0xFFFF0000u); }

// ---------------------------------------------------------------------------
// Algebra: relu((A'@E)@W^T + b) == relu(A'@(E@W^T) + b).  EW = E@W^T is
// graph-independent -> computed in heterogeneous K1 concurrently with the
// per-batch graph build.  K2 is wave-per-OUTPUT-row.
// R15 delta vs R14: adjacency entries carry the dest in-degree
// (adj = j | indeg<<12, indeg <= 2016 fits 11 bits), so K2's edge loop
// recomputes s_j = sqrt(1+indeg) in VALU instead of a dependent 4B gather —
// the per-edge chain shrinks from adj->s[j]->EW[j] to adj->EW[j].
//
// ws layout (words), all write-before-read (0xAA-poison safe):
//   rowptr 32832 | adj 16384 | s 32768 | te 16384 | EWb (bf16) 2097152
// ---------------------------------------------------------------------------

// K1: blocks 0..7 per-batch graph build (dedupe->CSR + s); blocks 8..23 te
// table; blocks 24..535 MFMA EW tiles. Dynamic LDS union: build 41KB,
// gemm 52.2KB -> smem 52224B = 3 blocks/CU.
__global__ __launch_bounds__(1024) void mega(const int* __restrict__ hist,
                                             const int* __restrict__ cur,
                                             const float* __restrict__ E,
                                             const float* __restrict__ W,
                                             unsigned* __restrict__ rowptr,
                                             unsigned* __restrict__ adj,
                                             float* __restrict__ s,
                                             float* __restrict__ te,
                                             unsigned short* __restrict__ EWb) {
    extern __shared__ unsigned smem_u[];
    const int tid = threadIdx.x;

    if (blockIdx.x >= BB + 16) {                   // ---- EW GEMM tiles ----
        unsigned short* Abf = (unsigned short*)smem_u;         // [64][136]
        unsigned short* Wb  = Abf + 64 * 136;                  // [128][136]
        const int r0 = (blockIdx.x - BB - 16) * 64;            // global row
        for (int idx = tid; idx < 2048; idx += 1024) {         // stage E tile
            int row = idx >> 5, c4 = idx & 31;
            float4 v = ((const float4*)E)[(size_t)(r0 + row) * 32 + c4];
            ushort4 o;
            o.x = f32_to_bf16_rtn(v.x); o.y = f32_to_bf16_rtn(v.y);
            o.z = f32_to_bf16_rtn(v.z); o.w = f32_to_bf16_rtn(v.w);
            *(ushort4*)&Abf[row * 136 + c4 * 4] = o;
        }
        for (int idx = tid; idx < 4096; idx += 1024) {         // stage W [n][k]
            int n = idx >> 5, c4 = idx & 31;
            float4 v = ((const float4*)W)[idx];
            ushort4 o;
            o.x = f32_to_bf16_rtn(v.x); o.y = f32_to_bf16_rtn(v.y);
            o.z = f32_to_bf16_rtn(v.z); o.w = f32_to_bf16_rtn(v.w);
            *(ushort4*)&Wb[n * 136 + c4 * 4] = o;
        }
        __syncthreads();
        const int lane = tid & 63, wv = tid >> 6;
        const int l15 = lane & 15, l4 = lane >> 4;
        const int rb = (wv >> 2) * 16;             // wave row base (0..48)
        const int cb = (wv & 3) * 32;              // wave col base (0..96)
        f32x4 acc[2] = {{0.f, 0.f, 0.f, 0.f}, {0.f, 0.f, 0.f, 0.f}};
#pragma unroll
        for (int kt = 0; kt < 4; ++kt) {
            bf16x8 a = *(const bf16x8*)&Abf[(rb + l15) * 136 + kt * 32 + l4 * 8];
#pragma unroll
            for (int nt = 0; nt < 2; ++nt) {
                bf16x8 bb = *(const bf16x8*)&Wb[(cb + nt * 16 + l15) * 136 + kt * 32 + l4 * 8];
                acc[nt] = __builtin_amdgcn_mfma_f32_16x16x32_bf16(a, bb, acc[nt], 0, 0, 0);
            }
        }
#pragma unroll
        for (int nt = 0; nt < 2; ++nt) {
            int col = cb + nt * 16 + l15;
#pragma unroll
            for (int i = 0; i < 4; ++i) {
                int row = r0 + rb + l4 * 4 + i;
                EWb[(size_t)row * 128 + col] = f32_to_bf16_rtn(acc[nt][i]);
            }
        }
        return;
    }
    if (blockIdx.x >= BB) {                        // ---- te table ----
        int g = (blockIdx.x - BB) * 1024 + tid;    // S*256 = 16384
        int t = g >> 8, c = g & 255, k = c >> 1;
        float ang = (float)t * powf(10000.0f, -(float)k / 128.0f);
        te[g] = (c & 1) ? cosf(ang) : sinf(ang);
        return;
    }

    // ---- graph build (one block per batch) ----
    unsigned* table = smem_u;              // 4096 hash set; ALIASED as pref later
    unsigned* cnt   = table + 4096;        // in-deg low16 | out-deg high16
    unsigned* lkeys = cnt + 4096;          // 2048 unique edge keys
    unsigned* wbase = lkeys + 2048;        // 17
    unsigned* totalp = wbase + 17;
    const int b = blockIdx.x;
    const int lane = tid & 63, wv = tid >> 6;

#pragma unroll
    for (int r = 0; r < 4; ++r) {
        int g = tid + r * 1024;
        table[g] = 0xFFFFFFFFu;
        cnt[g] = 0u;
    }
    if (tid == 0) *totalp = 0u;
    __syncthreads();

    for (int t = tid; t < HH * (SS - 1); t += 1024) {   // edge dedupe
        int h = t / 63, ss = t - h * 63;
        int base = (b * HH + h) * SS + ss;
        int i = hist[base], j = hist[base + 1];
        if (i != j) {
            unsigned key = ((unsigned)i << 12) | (unsigned)j;
            unsigned hh = (key * 2654435761u) >> 20;
            for (;;) {
                hh &= 4095u;
                unsigned old = atomicCAS(&table[hh], 0xFFFFFFFFu, key);
                if (old == 0xFFFFFFFFu) {
                    unsigned slot = atomicAdd(totalp, 1u);
                    lkeys[slot] = key;
                    atomicAdd(&cnt[key & 4095u], 1u);         // in-degree
                    atomicAdd(&cnt[key >> 12], 1u << 16);     // out-degree
                    break;
                }
                if (old == key) break;
                ++hh;
            }
        }
    }
    __syncthreads();                               // table (hash) now dead

#pragma unroll
    for (int r = 0; r < 4; ++r) {                  // s from in-degree
        int g = tid + r * 1024;
        s[b * CC + g] = sqrtf(1.0f + (float)(cnt[g] & 0xFFFFu));
    }

    // scan over out-degree -> CSR rowptr (pref aliases the dead hash table)
    unsigned* pref = table;
    {
        unsigned v0 = cnt[tid * 4]     >> 16;
        unsigned v1 = cnt[tid * 4 + 1] >> 16;
        unsigned v2 = cnt[tid * 4 + 2] >> 16;
        unsigned v3 = cnt[tid * 4 + 3] >> 16;
        unsigned tsum = v0 + v1 + v2 + v3;
        unsigned x = tsum;
#pragma unroll
        for (int off = 1; off < 64; off <<= 1) {
            unsigned y = __shfl_up(x, off);
            if (lane >= off) x += y;
        }
        if (lane == 63) wbase[wv + 1] = x;
        __syncthreads();
        if (tid == 0) {
            wbase[0] = 0u;
            for (int w = 1; w <= 16; ++w) wbase[w] += wbase[w - 1];
        }
        __syncthreads();
        unsigned texcl = wbase[wv] + x - tsum;
        pref[tid * 4]     = texcl;
        pref[tid * 4 + 1] = texcl + v0;
        pref[tid * 4 + 2] = texcl + v0 + v1;
        pref[tid * 4 + 3] = texcl + v0 + v1 + v2;
        __syncthreads();
#pragma unroll
        for (int r = 0; r < 4; ++r) {
            int g = tid + r * 1024;
            rowptr[b * 4104 + g] = pref[g];
        }
        if (tid == 0) rowptr[b * 4104 + 4096] = wbase[16];
    }
    __syncthreads();
    // outdeg (high16 of cnt) is now dead (encoded in rowptr) -> reuse the
    // high bits as the scatter cursor; KEEP indeg in the low bits so the
    // scatter can pack it into the adjacency entry.
#pragma unroll
    for (int r = 0; r < 4; ++r) {
        int g = tid + r * 1024;
        cnt[g] &= 0xFFFFu;
    }
    __syncthreads();

    {   // adjacency scatter in CSR order; entry = j | indeg_j << 12
        unsigned total = *totalp;
        for (int e = tid; e < (int)total; e += 1024) {
            unsigned key = lkeys[e];
            unsigned i = key >> 12, j = key & 4095u;
            unsigned old = atomicAdd(&cnt[i], 1u << 16);      // cursor in high bits
            unsigned pos = pref[i] + (old >> 16);
            unsigned indegj = cnt[j] & 0xFFFFu;               // low bits stable
            adj[b * 2048 + pos] = j | (indegj << 12);
        }
    }
}

// K2: one wave per OUTPUT row. cand uniform per wave (scalar chain), EW/E/te
// vector reads per lane, one coalesced 1KB row write. Per-edge chain is
// adj -> EW[j] only (s_j recomputed from the packed in-degree).
__global__ __launch_bounds__(256) void apply_out(const int* __restrict__ hist,
                                                 const int* __restrict__ cur,
                                                 const float* __restrict__ E,
                                                 const float* __restrict__ s,
                                                 const unsigned* __restrict__ rowptr,
                                                 const unsigned* __restrict__ adj,
                                                 const unsigned short* __restrict__ EWb,
                                                 const float* __restrict__ bg,
                                                 const float* __restrict__ te,
                                                 float* __restrict__ out) {
    const int g = blockIdx.x * 256 + threadIdx.x;
    const int row = g >> 6, lane = g & 63;
    int b, spos, cand;
    if (row < BB * HH * SS) {
        spos = row & 63;
        b = row >> 11;
        cand = hist[row];
    } else {
        int rc = row - BB * HH * SS;
        spos = rc & 63;
        b = rc >> 6;
        cand = cur[rc];
    }
    const unsigned* ew = (const unsigned*)EWb;     // 64 u32 per row (128 bf16)
    const float si = s[b * CC + cand];
    unsigned u = ew[(size_t)(b * CC + cand) * 64 + lane];
    float ax = si * bf16lo(u), ay = si * bf16hi(u);
    unsigned p0 = rowptr[b * 4104 + cand], p1 = rowptr[b * 4104 + cand + 1];
    for (unsigned p = p0; p < p1; ++p) {
        unsigned e = adj[b * 2048 + p];
        unsigned j = e & 4095u;
        float sj = sqrtf(1.0f + (float)(e >> 12));
        unsigned uj = ew[(size_t)(b * CC + j) * 64 + lane];
        ax += sj * bf16lo(uj);
        ay += sj * bf16hi(uj);
    }
    float2 bgv = ((const float2*)bg)[lane];
    ax = fmaxf(si * ax + bgv.x, 0.f);
    ay = fmaxf(si * ay + bgv.y, 0.f);
    float2 e2 = ((const float2*)E)[(size_t)(b * CC + cand) * 64 + lane];

    const float2* te2 = (const float2*)te;
    float2 t0 = te2[spos * 128 + lane];
    float2 t1 = te2[spos * 128 + 64 + lane];
    float2* out2 = (float2*)out;
    out2[(size_t)row * 128 + lane]      = make_float2(ax + t0.x, ay + t0.y);
    out2[(size_t)row * 128 + 64 + lane] = make_float2(e2.x + t1.x, e2.y + t1.y);
}

extern "C" void kernel_launch(void* const* d_in, const int* in_sizes, int n_in,
                              void* d_out, int out_size, void* d_ws, size_t ws_size,
                              hipStream_t stream) {
    const int*   hist = (const int*)d_in[1];
    const int*   cur  = (const int*)d_in[2];
    const float* E    = (const float*)d_in[3];
    const float* W    = (const float*)d_in[4];
    const float* bg   = (const float*)d_in[5];
    float* out = (float*)d_out;

    unsigned* ws_u   = (unsigned*)d_ws;
    unsigned* rowptr = ws_u;                          // 32832
    unsigned* adj    = rowptr + 32832;                // 16384
    float*    sarr   = (float*)(adj + 16384);         // 32768
    float*    te     = sarr + 32768;                  // 16384
    unsigned short* EWb = (unsigned short*)(te + 16384);  // 4194304 shorts

    mega<<<BB + 16 + 512, 1024, 52224, stream>>>(hist, cur, E, W, rowptr, adj,
                                                 sarr, te, EWb);
    apply_out<<<(BB * HH * SS + BB * SS) / 4, 256, 0, stream>>>(
        hist, cur, E, sarr, rowptr, adj, EWb, bg, te, out);
}